// Round 1
// baseline (419.032 us; speedup 1.0000x reference)
//
#include <hip/hip_runtime.h>

typedef _Float16 half8_t __attribute__((ext_vector_type(8)));
typedef float    f32x4_t __attribute__((ext_vector_type(4)));

#define OUT_HALF 1351680   // 4096*330

__device__ __forceinline__ float fast_silu(float x) {
    float e = __builtin_amdgcn_exp2f(x * -1.44269504f);
    return x * __builtin_amdgcn_rcpf(1.0f + e);
}

__device__ __forceinline__ float fast_softplus(float x) {
    // log1p(exp(x)); inputs here bounded ~[-25, 25]
    float e = __builtin_amdgcn_exp2f(x * 1.44269504f);
    return __builtin_amdgcn_logf(1.0f + e) * 0.69314718f;
}

// ---- prep: x[4096][40] fp32 -> x16[4096][64] f16, col40 = 1.0 (bias lane), 41..63 = 0
__global__ __launch_bounds__(256) void prep_x_kernel(const float* __restrict__ x,
                                                     _Float16* __restrict__ x16) {
    int idx = blockIdx.x * 256 + threadIdx.x;
    if (idx >= 4096 * 64) return;
    int b = idx >> 6, cc = idx & 63;
    float v = (cc < 40) ? x[b * 40 + cc] : (cc == 40 ? 1.0f : 0.0f);
    x16[idx] = (_Float16)v;
}

// ---- fused 3-layer ensemble MLP, one (d,e) per block, 512 batch rows per block
__global__ __launch_bounds__(256, 2) void mlp_kernel(
    const _Float16* __restrict__ x16,
    const float* __restrict__ W1, const float* __restrict__ b1,
    const float* __restrict__ W2, const float* __restrict__ b2,
    const float* __restrict__ W3, const float* __restrict__ b3,
    float* __restrict__ out)
{
    __shared__ _Float16 w2s[128 * 136];   // rows padded 128->136 halves (bank decorrelation)
    __shared__ float    b2s[128];

    const int bid   = blockIdx.x;
    const int de    = bid >> 3;
    const int chunk = bid & 7;
    const int tid   = threadIdx.x;
    const int wave  = tid >> 6;
    const int lane  = tid & 63;
    const int c     = lane & 15;   // MFMA: A.m / B.n / C.col
    const int q     = lane >> 4;   // MFMA quad

    // ---- stage W2 (fp32 global -> f16 LDS) with sigma-permutation baked in:
    // w2s[g][32*kf + 8*q + j] = W2[g][32*kf + 16*(j>>2) + 4*q + (j&3)]
    {
        const float* W2g = W2 + (size_t)de * 16384;
        for (int i = tid; i < 2048; i += 256) {
            int g  = i >> 4;
            int kf = (i >> 2) & 3;
            int qq = i & 3;
            f32x4_t a = *(const f32x4_t*)&W2g[g * 128 + kf * 32 + qq * 4];
            f32x4_t bb = *(const f32x4_t*)&W2g[g * 128 + kf * 32 + 16 + qq * 4];
            union { _Float16 hh[8]; half8_t v; } u;
            u.hh[0] = (_Float16)a[0]; u.hh[1] = (_Float16)a[1];
            u.hh[2] = (_Float16)a[2]; u.hh[3] = (_Float16)a[3];
            u.hh[4] = (_Float16)bb[0]; u.hh[5] = (_Float16)bb[1];
            u.hh[6] = (_Float16)bb[2]; u.hh[7] = (_Float16)bb[3];
            *(half8_t*)&w2s[g * 136 + kf * 32 + qq * 8] = u.v;
        }
        if (tid < 128) b2s[tid] = b2[de * 128 + tid];
    }
    __syncthreads();

    // ---- hoist W1 fragments (natural k order; b1 folded via x col 40)
    const float* W1g = W1 + (size_t)de * (128 * 40);
    const float* b1g = b1 + (size_t)de * 128;
    half8_t w1frag[8][2];
    #pragma unroll
    for (int ht = 0; ht < 8; ht++) {
        const int h = ht * 16 + c;
        {   // kf = 0: cols q*8 .. q*8+7 (< 32)
            f32x4_t a = *(const f32x4_t*)&W1g[h * 40 + q * 8];
            f32x4_t bb = *(const f32x4_t*)&W1g[h * 40 + q * 8 + 4];
            union { _Float16 hh[8]; half8_t v; } u;
            #pragma unroll
            for (int r = 0; r < 4; r++) { u.hh[r] = (_Float16)a[r]; u.hh[4 + r] = (_Float16)bb[r]; }
            w1frag[ht][0] = u.v;
        }
        {   // kf = 1: cols 32+q*8 .. +7 ; col40 = b1, >40 = 0
            union { _Float16 hh[8]; half8_t v; } u;
            #pragma unroll
            for (int r = 0; r < 8; r++) u.hh[r] = (_Float16)0.0f;
            if (q == 0) {
                f32x4_t a = *(const f32x4_t*)&W1g[h * 40 + 32];
                f32x4_t bb = *(const f32x4_t*)&W1g[h * 40 + 36];
                #pragma unroll
                for (int r = 0; r < 4; r++) { u.hh[r] = (_Float16)a[r]; u.hh[4 + r] = (_Float16)bb[r]; }
            } else if (q == 1) {
                u.hh[0] = (_Float16)b1g[h];
            }
            w1frag[ht][1] = u.v;
        }
    }

    // ---- hoist W3 as layer-3 MFMA A-fragments (sigma-permuted); rows >=2 zero
    const float* W3g = W3 + (size_t)de * 256;
    half8_t w3frag[4];
    #pragma unroll
    for (int kf = 0; kf < 4; kf++) {
        union { _Float16 hh[8]; half8_t v; } u;
        #pragma unroll
        for (int r = 0; r < 8; r++) u.hh[r] = (_Float16)0.0f;
        if (c < 2) {
            f32x4_t a = *(const f32x4_t*)&W3g[c * 128 + kf * 32 + q * 4];
            f32x4_t bb = *(const f32x4_t*)&W3g[c * 128 + kf * 32 + 16 + q * 4];
            #pragma unroll
            for (int r = 0; r < 4; r++) { u.hh[r] = (_Float16)a[r]; u.hh[4 + r] = (_Float16)bb[r]; }
        }
        w3frag[kf] = u.v;
    }

    const float b3m = b3[de * 2 + 0];
    const float b3l = b3[de * 2 + 1];
    const f32x4_t zero4 = {0.f, 0.f, 0.f, 0.f};
    // layer-3 C init: rows 0/1 (q==0, regs 0/1) carry b3
    f32x4_t c3init = zero4;
    if (q == 0) { c3init[0] = b3m; c3init[1] = b3l; }

    #pragma unroll 1
    for (int it = 0; it < 4; it++) {
        const int b0 = chunk * 512 + it * 128 + wave * 32;

        // x fragments (B operand), direct from L2-resident x16
        half8_t xf[2][2];
        #pragma unroll
        for (int nt = 0; nt < 2; nt++)
            #pragma unroll
            for (int kf = 0; kf < 2; kf++)
                xf[nt][kf] = *(const half8_t*)&x16[(b0 + nt * 16 + c) * 64 + kf * 32 + q * 8];

        // ---- layer 1: D1[h][b] = W1 . xT  (bias via k=40)
        f32x4_t acc1[8][2];
        #pragma unroll
        for (int ht = 0; ht < 8; ht++)
            #pragma unroll
            for (int nt = 0; nt < 2; nt++) {
                f32x4_t a = __builtin_amdgcn_mfma_f32_16x16x32_f16(w1frag[ht][0], xf[nt][0], zero4, 0, 0, 0);
                acc1[ht][nt] = __builtin_amdgcn_mfma_f32_16x16x32_f16(w1frag[ht][1], xf[nt][1], a, 0, 0, 0);
            }

        // silu + pack -> P[ht][nt][p] (these ARE layer-2 B-fragment halves under sigma)
        unsigned P[8][2][2];
        #pragma unroll
        for (int ht = 0; ht < 8; ht++)
            #pragma unroll
            for (int nt = 0; nt < 2; nt++)
                #pragma unroll
                for (int p = 0; p < 2; p++) {
                    float v0 = fast_silu(acc1[ht][nt][2 * p + 0]);
                    float v1 = fast_silu(acc1[ht][nt][2 * p + 1]);
                    P[ht][nt][p] = __builtin_bit_cast(unsigned, __builtin_amdgcn_cvt_pkrtz(v0, v1));
                }

        // ---- layer 2: D2[g][b] = W2 . h1 + b2 (bias via C init)
        f32x4_t acc2[8][2];
        #pragma unroll
        for (int mt = 0; mt < 8; mt++) {
            f32x4_t binit = *(const f32x4_t*)&b2s[mt * 16 + q * 4];
            acc2[mt][0] = binit;
            acc2[mt][1] = binit;
        }
        #pragma unroll
        for (int kf = 0; kf < 4; kf++) {
            half8_t af[8];
            #pragma unroll
            for (int mt = 0; mt < 8; mt++)
                af[mt] = *(const half8_t*)&w2s[(mt * 16 + c) * 136 + kf * 32 + q * 8];
            #pragma unroll
            for (int nt = 0; nt < 2; nt++) {
                union { unsigned u[4]; half8_t h; } bu;
                bu.u[0] = P[2 * kf][nt][0];
                bu.u[1] = P[2 * kf][nt][1];
                bu.u[2] = P[2 * kf + 1][nt][0];
                bu.u[3] = P[2 * kf + 1][nt][1];
                #pragma unroll
                for (int mt = 0; mt < 8; mt++)
                    acc2[mt][nt] = __builtin_amdgcn_mfma_f32_16x16x32_f16(af[mt], bu.h, acc2[mt][nt], 0, 0, 0);
            }
        }

        // silu + pack h2
        unsigned P2[8][2][2];
        #pragma unroll
        for (int mt = 0; mt < 8; mt++)
            #pragma unroll
            for (int nt = 0; nt < 2; nt++)
                #pragma unroll
                for (int p = 0; p < 2; p++) {
                    float v0 = fast_silu(acc2[mt][nt][2 * p + 0]);
                    float v1 = fast_silu(acc2[mt][nt][2 * p + 1]);
                    P2[mt][nt][p] = __builtin_bit_cast(unsigned, __builtin_amdgcn_cvt_pkrtz(v0, v1));
                }

        // ---- layer 3: D3[o][b] via one MFMA chain (rows 0/1 valid, b3 via C init)
        #pragma unroll
        for (int nt = 0; nt < 2; nt++) {
            f32x4_t acc3 = c3init;
            #pragma unroll
            for (int kf = 0; kf < 4; kf++) {
                union { unsigned u[4]; half8_t h; } bu;
                bu.u[0] = P2[2 * kf][nt][0];
                bu.u[1] = P2[2 * kf][nt][1];
                bu.u[2] = P2[2 * kf + 1][nt][0];
                bu.u[3] = P2[2 * kf + 1][nt][1];
                acc3 = __builtin_amdgcn_mfma_f32_16x16x32_f16(w3frag[kf], bu.h, acc3, 0, 0, 0);
            }
            if (q == 0) {
                const int bg = b0 + nt * 16 + c;
                float vm = acc3[0];
                float vl = acc3[1];
                vl = 5.0f - fast_softplus(5.0f - vl);
                vl = -10.0f + fast_softplus(vl + 10.0f);
                out[(size_t)bg * 330 + de] = vm;
                out[(size_t)OUT_HALF + (size_t)bg * 330 + de] = vl;
            }
        }
    }
}

extern "C" void kernel_launch(void* const* d_in, const int* in_sizes, int n_in,
                              void* d_out, int out_size, void* d_ws, size_t ws_size,
                              hipStream_t stream) {
    (void)in_sizes; (void)n_in; (void)out_size; (void)ws_size;
    const float* x  = (const float*)d_in[0];
    const float* W1 = (const float*)d_in[1];
    const float* b1 = (const float*)d_in[2];
    const float* W2 = (const float*)d_in[3];
    const float* b2 = (const float*)d_in[4];
    const float* W3 = (const float*)d_in[5];
    const float* b3 = (const float*)d_in[6];
    _Float16* x16 = (_Float16*)d_ws;            // 4096*64 halves = 512 KB
    float* out = (float*)d_out;

    hipLaunchKernelGGL(prep_x_kernel, dim3(1024), dim3(256), 0, stream, x, x16);
    hipLaunchKernelGGL(mlp_kernel, dim3(2640), dim3(256), 0, stream,
                       x16, W1, b1, W2, b2, W3, b3, out);
}